// Round 14
// baseline (7397.145 us; speedup 1.0000x reference)
//
#include <hip/hip_runtime.h>
#include <math.h>

#define DEVINL __device__ __forceinline__
typedef float f32x4 __attribute__((ext_vector_type(4)));

// ---------------------------------------------------------------------------
// RSSM scan, multi-launch. R14 = R12 loop (best: 6.94 ms) + R13 epilogue:
//   loop:  dyn(208) | dynfin(32) | gru(128) | q0+x0(160) | qo256(256) |
//          finx12(64: x1x2 + x0fin)
//   epilogue: batched prior with 64-row tiles.
// RULE (R13 lesson): loop-phase grids must be <= 256 (1 WG/CU) or the
// overflow WGs serialize as a second scheduling wave (+0.35ms/64 steps).
// Launch boundaries are the only sync (in-kernel correct barrier >= 30us
// wbl2 floor > 12us launch gap; relaxed sync unsound on gfx950).
// fp32 throughout (bf16 would flip argmaxes -> cascading recurrence error).
// ---------------------------------------------------------------------------

struct RPtrs {
  const float *embed, *action; const int *is_first;
  const float *W_in_deter, *b_in_deter, *g_in_deter;
  const float *W_in_stoch, *b_in_stoch, *g_in_stoch;
  const float *W_in_act,   *b_in_act,   *g_in_act;
  const float *W_dyn, *b_dyn, *g_dyn;
  const float *W_gru, *b_gru;
  const float *W_p0, *b_p0, *g_p0;
  const float *W_p1, *b_p1, *g_p1;
  const float *W_po, *b_po;
  const float *W_q0, *b_q0, *g_q0;
  const float *W_qo, *b_qo;
  float *out_post, *out_prior, *out_deters;
  float *deter, *determ, *xact, *hact;
  float *SDyn, *SQ0, *SX0, *Abuf0, *Abuf1;
  int *sidxg;
};

// ---- A loaders ------------------------------------------------------------
struct LdPlain {
  const float* A; int lda;
  DEVINL const float* addr(int r, int k) const { return A + (size_t)r * lda + k; }
};
struct LdDyn {   // [dg(256 masked deter) | x(3072 activated)]
  const float* dm; const float* x; int blk;
  DEVINL const float* addr(int r, int k) const {
    return (k < 256) ? dm + (size_t)r * 2048 + blk * 256 + k
                     : x + (size_t)r * 3072 + (k - 256);
  }
};
struct LdQ0 {    // [deter(2048) | embed(1024)]
  const float* det; const float* emb; int t;
  DEVINL const float* addr(int r, int k) const {
    return (k < 2048) ? det + (size_t)r * 2048 + k
                      : emb + ((size_t)r * 64 + t) * 1024 + (k - 2048);
  }
};

#define FMA4(A, S, W) { (A)[0]=fmaf((S),(W)[0],(A)[0]); (A)[1]=fmaf((S),(W)[1],(A)[1]); \
                        (A)[2]=fmaf((S),(W)[2],(A)[2]); (A)[3]=fmaf((S),(W)[3],(A)[3]); }

// ---- GEMM (K-chunked, slab output): 256 cols x 32 rows x (NBLK*64) K ------
template <int NBLK, typename LA>
DEVINL void gemm_tile(LA la, const float* __restrict__ W, int ldw, int wcb,
                      int k0, float* __restrict__ slab, int sst, int scb,
                      const float* __restrict__ bias, float* As) {
  const int tid = threadIdx.x;
  const int c4 = (tid & 63) * 4;
  const int rg = (tid >> 6) * 8;
  const int srr = tid & 31;
  const int skk = (tid >> 5) * 8;
  f32x4 acc[8];
#pragma unroll
  for (int i = 0; i < 8; ++i) acc[i] = (f32x4){0.f, 0.f, 0.f, 0.f};
  const float* ap = la.addr(srr, k0 + skk);
  f32x4 cur0 = *(const f32x4*)ap;
  f32x4 cur1 = *(const f32x4*)(ap + 4);
#pragma unroll
  for (int b = 0; b < NBLK; ++b) {
    __syncthreads();
#pragma unroll
    for (int e = 0; e < 4; ++e) {
      As[(skk + e) * 36 + srr]     = cur0[e];
      As[(skk + 4 + e) * 36 + srr] = cur1[e];
    }
    f32x4 nxt0, nxt1;
    if (b + 1 < NBLK) {
      const float* np = la.addr(srr, k0 + (b + 1) * 64 + skk);
      nxt0 = *(const f32x4*)np;
      nxt1 = *(const f32x4*)(np + 4);
    }
    __syncthreads();
    const float* Wp = W + (size_t)(k0 + b * 64) * ldw + wcb + c4;
#pragma unroll 8
    for (int kk = 0; kk < 64; ++kk) {
      f32x4 w = *(const f32x4*)(Wp + (size_t)kk * ldw);
      const float* Ab = As + kk * 36 + rg;
      f32x4 alo = *(const f32x4*)(Ab);
      f32x4 ahi = *(const f32x4*)(Ab + 4);
      FMA4(acc[0], alo[0], w); FMA4(acc[1], alo[1], w);
      FMA4(acc[2], alo[2], w); FMA4(acc[3], alo[3], w);
      FMA4(acc[4], ahi[0], w); FMA4(acc[5], ahi[1], w);
      FMA4(acc[6], ahi[2], w); FMA4(acc[7], ahi[3], w);
    }
    if (b + 1 < NBLK) { cur0 = nxt0; cur1 = nxt1; }
  }
  f32x4 bv = (f32x4){0.f, 0.f, 0.f, 0.f};
  if (bias) bv = *(const f32x4*)(bias + wcb + c4);
#pragma unroll
  for (int i = 0; i < 8; ++i) {
    f32x4 o = acc[i] + bv;
    *(f32x4*)(slab + (size_t)(rg + i) * sst + scb + c4) = o;
  }
}

// ---- epilogue GEMM: 256 cols x 64 rows x full K, direct out + bias --------
template <typename LA>
DEVINL void gemm_big64(LA la, const float* __restrict__ W, int ldw, int wcb,
                       int nblk, float* __restrict__ outp, int ost,
                       const float* __restrict__ bias, float* As) {
  const int tid = threadIdx.x;
  const int c4 = (tid & 63) * 4;
  const int rg = (tid >> 6) * 16;   // 16 rows per wave
  const int srr = tid & 63;         // staging row 0..63
  const int skk = (tid >> 6) * 16;  // staging k-offset (16 k per wave)
  f32x4 acc[16];
#pragma unroll
  for (int i = 0; i < 16; ++i) acc[i] = (f32x4){0.f, 0.f, 0.f, 0.f};
  const float* ap = la.addr(srr, skk);
  f32x4 cur0 = *(const f32x4*)ap;
  f32x4 cur1 = *(const f32x4*)(ap + 4);
  f32x4 cur2 = *(const f32x4*)(ap + 8);
  f32x4 cur3 = *(const f32x4*)(ap + 12);
  for (int b = 0; b < nblk; ++b) {
    __syncthreads();
#pragma unroll
    for (int e = 0; e < 4; ++e) {
      As[(skk + e) * 68 + srr]      = cur0[e];
      As[(skk + 4 + e) * 68 + srr]  = cur1[e];
      As[(skk + 8 + e) * 68 + srr]  = cur2[e];
      As[(skk + 12 + e) * 68 + srr] = cur3[e];
    }
    f32x4 nxt0, nxt1, nxt2, nxt3;
    if (b + 1 < nblk) {
      const float* np = la.addr(srr, (b + 1) * 64 + skk);
      nxt0 = *(const f32x4*)np;
      nxt1 = *(const f32x4*)(np + 4);
      nxt2 = *(const f32x4*)(np + 8);
      nxt3 = *(const f32x4*)(np + 12);
    }
    __syncthreads();
    const float* Wp = W + (size_t)(b * 64) * ldw + wcb + c4;
#pragma unroll 4
    for (int kk = 0; kk < 64; ++kk) {
      f32x4 w = *(const f32x4*)(Wp + (size_t)kk * ldw);
      const float* Ab = As + kk * 68 + rg;
      f32x4 a0 = *(const f32x4*)(Ab);
      f32x4 a1 = *(const f32x4*)(Ab + 4);
      f32x4 a2 = *(const f32x4*)(Ab + 8);
      f32x4 a3 = *(const f32x4*)(Ab + 12);
      FMA4(acc[0],  a0[0], w); FMA4(acc[1],  a0[1], w);
      FMA4(acc[2],  a0[2], w); FMA4(acc[3],  a0[3], w);
      FMA4(acc[4],  a1[0], w); FMA4(acc[5],  a1[1], w);
      FMA4(acc[6],  a1[2], w); FMA4(acc[7],  a1[3], w);
      FMA4(acc[8],  a2[0], w); FMA4(acc[9],  a2[1], w);
      FMA4(acc[10], a2[2], w); FMA4(acc[11], a2[3], w);
      FMA4(acc[12], a3[0], w); FMA4(acc[13], a3[1], w);
      FMA4(acc[14], a3[2], w); FMA4(acc[15], a3[3], w);
    }
    if (b + 1 < nblk) { cur0 = nxt0; cur1 = nxt1; cur2 = nxt2; cur3 = nxt3; }
  }
  f32x4 bv = *(const f32x4*)(bias + wcb + c4);
#pragma unroll
  for (int i = 0; i < 16; ++i) {
    f32x4 o = acc[i] + bv;
    *(f32x4*)(outp + (size_t)(rg + i) * ost + wcb + c4) = o;
  }
}

// ---- finalizer: y = sum chunks (regs, ascending), RMS, SiLU ---------------
DEVINL void act_fin(const float* __restrict__ slab, int N, int nch, int r,
                    const float* __restrict__ g, float* __restrict__ out,
                    float invN, float* red) {
  const int tid = threadIdx.x;
  const size_t cstr = (size_t)32 * N;
  const float* base = slab + (size_t)r * N + tid * 4;
  f32x4 y0 = (f32x4){0.f, 0.f, 0.f, 0.f}, y1 = y0;
  for (int ch = 0; ch < nch; ++ch)
    y0 += *(const f32x4*)(base + (size_t)ch * cstr);
  float ss = y0[0]*y0[0] + y0[1]*y0[1] + y0[2]*y0[2] + y0[3]*y0[3];
  if (N == 2048) {
    for (int ch = 0; ch < nch; ++ch)
      y1 += *(const f32x4*)(base + 1024 + (size_t)ch * cstr);
    ss += y1[0]*y1[0] + y1[1]*y1[1] + y1[2]*y1[2] + y1[3]*y1[3];
  }
#pragma unroll
  for (int o = 32; o > 0; o >>= 1) ss += __shfl_down(ss, o, 64);
  if ((tid & 63) == 0) red[tid >> 6] = ss;
  __syncthreads();
  if (tid == 0)
    red[4] = 1.f / sqrtf((red[0] + red[1] + red[2] + red[3]) * invN + 1e-6f);
  __syncthreads();
  const float sc = red[4];
  {
    f32x4 gg = *(const f32x4*)(g + tid * 4);
    f32x4 v = y0 * sc * gg;
#pragma unroll
    for (int k = 0; k < 4; ++k) v[k] = v[k] / (1.f + expf(-v[k]));
    *(f32x4*)(out + tid * 4) = v;
  }
  if (N == 2048) {
    f32x4 gg = *(const f32x4*)(g + 1024 + tid * 4);
    f32x4 v = y1 * sc * gg;
#pragma unroll
    for (int k = 0; k < 4; ++k) v[k] = v[k] / (1.f + expf(-v[k]));
    *(f32x4*)(out + 1024 + tid * 4) = v;
  }
  __syncthreads();
}

DEVINL float sigm(float x) { return 1.f / (1.f + expf(-x)); }

// ---- x2 (action) pre-act + RMS + SiLU for row r, step tt ------------------
DEVINL void x2_row(const RPtrs& p, int tt, int r, float m, float* red) {
  const int tid = threadIdx.x;
  const int c0 = tid * 4;
  const float* arow = p.action + ((size_t)r * 64 + tt) * 16;
  f32x4 s2 = *(const f32x4*)(p.b_in_act + c0);
#pragma unroll
  for (int ii = 0; ii < 16; ++ii) {
    float av = arow[ii] * m;
    av = av / fmaxf(fabsf(av), 1.f);
    f32x4 wv = *(const f32x4*)(p.W_in_act + ii * 1024 + c0);
    FMA4(s2, av, wv);
  }
  float ss = s2[0]*s2[0] + s2[1]*s2[1] + s2[2]*s2[2] + s2[3]*s2[3];
#pragma unroll
  for (int o = 32; o > 0; o >>= 1) ss += __shfl_down(ss, o, 64);
  if ((tid & 63) == 0) red[tid >> 6] = ss;
  __syncthreads();
  if (tid == 0)
    red[4] = 1.f / sqrtf((red[0] + red[1] + red[2] + red[3]) * (1.f / 1024.f) + 1e-6f);
  __syncthreads();
  float sc = red[4];
  f32x4 gg = *(const f32x4*)(p.g_in_act + c0);
  f32x4 v = s2 * sc * gg;
#pragma unroll
  for (int k = 0; k < 4; ++k) v[k] = v[k] / (1.f + expf(-v[k]));
  *(f32x4*)(p.xact + (size_t)r * 3072 + 2048 + c0) = v;
}

// ---- bias-only pre-act + RMS + SiLU (for t=0: determ=0, stoch=0) ----------
DEVINL void bias_row(const float* __restrict__ b, const float* __restrict__ g,
                     float* __restrict__ out, float* red) {
  const int tid = threadIdx.x;
  const int c0 = tid * 4;
  f32x4 pre = *(const f32x4*)(b + c0);
  float ss = pre[0]*pre[0] + pre[1]*pre[1] + pre[2]*pre[2] + pre[3]*pre[3];
#pragma unroll
  for (int o = 32; o > 0; o >>= 1) ss += __shfl_down(ss, o, 64);
  if ((tid & 63) == 0) red[tid >> 6] = ss;
  __syncthreads();
  if (tid == 0)
    red[4] = 1.f / sqrtf((red[0] + red[1] + red[2] + red[3]) * (1.f / 1024.f) + 1e-6f);
  __syncthreads();
  float sc = red[4];
  f32x4 gg = *(const f32x4*)(g + c0);
  f32x4 v = pre * sc * gg;
#pragma unroll
  for (int k = 0; k < 4; ++k) v[k] = v[k] / (1.f + expf(-v[k]));
  *(f32x4*)(out + c0) = v;
}

// ===========================================================================
// K0: init + prologue. grid 512: WGs 0-63 zero determ; WGs 480-511 xact(0)
__global__ __launch_bounds__(256) void k_init(RPtrs p) {
  __shared__ float red[8];
  const int wg = blockIdx.x;
  size_t i = (size_t)wg * 256 + threadIdx.x;
  if (i < 65536) p.determ[i] = 0.f;
  if (wg >= 480) {
    const int r = wg - 480;
    bias_row(p.b_in_deter, p.g_in_deter, p.xact + (size_t)r * 3072, red);
    __syncthreads();
    bias_row(p.b_in_stoch, p.g_in_stoch, p.xact + (size_t)r * 3072 + 1024, red);
    __syncthreads();
    float m = p.is_first[r * 64] ? 0.f : 1.f;
    x2_row(p, 0, r, m, red);
  }
}

// K1: dyn. grid 208
__global__ __launch_bounds__(256, 2) void k_dyn(RPtrs p, int t) {
  __shared__ __align__(16) float As[2304];
  const int wg = blockIdx.x;
  int blk = wg / 26, kc = wg % 26;  // KC=128
  LdDyn la{p.determ, p.xact, blk};
  gemm_tile<2>(la, p.W_dyn + (size_t)blk * 851968, 256, 0, kc * 128,
               p.SDyn + (size_t)kc * 65536, 2048, blk * 256,
               kc == 0 ? p.b_dyn + blk * 256 : nullptr, As);
}

// K2: dynfin. grid 32
__global__ __launch_bounds__(256, 2) void k_dynfin(RPtrs p) {
  __shared__ float red[8];
  act_fin(p.SDyn, 2048, 26, blockIdx.x, p.g_dyn,
          p.hact + (size_t)blockIdx.x * 2048, 1.f / 2048.f, red);
}

// K3: gru. grid 128
__global__ __launch_bounds__(256, 2) void k_gru(RPtrs p, int t) {
  __shared__ float Al[8704];
  const int wg = blockIdx.x;
  const int blk = wg >> 4, jch = wg & 15;
  const int tid = threadIdx.x;
  {
    const float* hp = p.hact + blk * 256 + tid;
#pragma unroll
    for (int jb = 0; jb < 32; ++jb)
      Al[tid * 34 + jb] = hp[(size_t)jb * 2048];
  }
  __syncthreads();
  const int j = tid & 15, rg = tid >> 4;
  const int r0 = rg * 2;
  const int jcol = jch * 16 + j;
  const float* Wg = p.W_gru + (size_t)blk * 196608 + jcol;
  float r0a = 0, r1a = 0, c0a = 0, c1a = 0, u0a = 0, u1a = 0;
#pragma unroll 4
  for (int kk = 0; kk < 256; ++kk) {
    float wr = Wg[(size_t)kk * 768];
    float wc = Wg[(size_t)kk * 768 + 256];
    float wu = Wg[(size_t)kk * 768 + 512];
    float ax = Al[kk * 34 + r0], ay = Al[kk * 34 + r0 + 1];
    r0a = fmaf(ax, wr, r0a); r1a = fmaf(ay, wr, r1a);
    c0a = fmaf(ax, wc, c0a); c1a = fmaf(ay, wc, c1a);
    u0a = fmaf(ax, wu, u0a); u1a = fmaf(ay, wu, u1a);
  }
  const int col = blk * 256 + jcol;
  const float br = p.b_gru[blk * 768 + jcol];
  const float bc = p.b_gru[blk * 768 + 256 + jcol];
  const float bu = p.b_gru[blk * 768 + 512 + jcol];
#pragma unroll
  for (int rr = 0; rr < 2; ++rr) {
    int r = r0 + rr;
    float gr = (rr ? r1a : r0a) + br;
    float gc = (rr ? c1a : c0a) + bc;
    float gu = (rr ? u1a : u0a) + bu;
    float rs = sigm(gr);
    float cc = tanhf(rs * gc);
    float uu = sigm(gu - 1.f);
    float dg = p.determ[(size_t)r * 2048 + col];
    float nd = uu * cc + (1.f - uu) * dg;
    p.deter[(size_t)r * 2048 + col] = nd;
    p.out_deters[((size_t)r * 64 + t) * 2048 + col] = nd;
    float mn = 0.f;
    if (t + 1 < 64) mn = p.is_first[r * 64 + (t + 1)] ? 0.f : 1.f;
    p.determ[(size_t)r * 2048 + col] = nd * mn;
  }
}

// K4: q0 (0-95) + x0(t+1) (96-159). grid 160
__global__ __launch_bounds__(256, 2) void k_q0x0(RPtrs p, int t) {
  __shared__ __align__(16) float As[2304];
  const int wg = blockIdx.x;
  if (wg < 96) {
    int ct = wg & 3, kc = wg >> 2;   // kc 0..23, KC=128, K=3072
    LdQ0 la{p.deter, p.embed, t};
    gemm_tile<2>(la, p.W_q0, 1024, ct * 256, kc * 128,
                 p.SQ0 + (size_t)kc * 32768, 1024, ct * 256,
                 kc == 0 ? p.b_q0 : nullptr, As);
  } else {
    if (t >= 63) return;
    int i = wg - 96, ct = i & 3, kc = i >> 2;   // kc 0..15, K=2048
    LdPlain la{p.determ, 2048};
    gemm_tile<2>(la, p.W_in_deter, 1024, ct * 256, kc * 128,
                 p.SX0 + (size_t)kc * 32768, 1024, ct * 256,
                 kc == 0 ? p.b_in_deter : nullptr, As);
  }
}

// K5: qo256. WG = (row r = wg>>3, col-chunk ch = wg&7 of 128 cols).
// q0fin (redundant x8), chunked GEMV, post logits + local argmax. grid 256
__global__ __launch_bounds__(256, 2) void k_qo256(RPtrs p, int t) {
  __shared__ __align__(16) float smem[2184];
  float* qrow = smem;             // 1024
  float* pbuf = smem + 1024;      // 1024
  float* ybuf = smem + 2048;      // 128
  float* red  = smem + 2176;      // 8
  const int wg = blockIdx.x;
  const int r = wg >> 3, ch = wg & 7;
  const int tid = threadIdx.x;
  const int c0 = tid * 4;
  {  // q0fin -> qrow (ascending chunk order)
    const float* base = p.SQ0 + (size_t)r * 1024 + c0;
    f32x4 y = (f32x4){0.f, 0.f, 0.f, 0.f};
#pragma unroll
    for (int cc = 0; cc < 24; ++cc) y += *(const f32x4*)(base + (size_t)cc * 32768);
    float ss = y[0]*y[0] + y[1]*y[1] + y[2]*y[2] + y[3]*y[3];
#pragma unroll
    for (int o = 32; o > 0; o >>= 1) ss += __shfl_down(ss, o, 64);
    if ((tid & 63) == 0) red[tid >> 6] = ss;
    __syncthreads();
    if (tid == 0)
      red[4] = 1.f / sqrtf((red[0] + red[1] + red[2] + red[3]) * (1.f / 1024.f) + 1e-6f);
    __syncthreads();
    float sc = red[4];
    f32x4 gg = *(const f32x4*)(p.g_q0 + c0);
    f32x4 v = y * sc * gg;
#pragma unroll
    for (int k = 0; k < 4; ++k) v[k] = v[k] / (1.f + expf(-v[k]));
    *(f32x4*)(qrow + c0) = v;
  }
  __syncthreads();
  const int cg = tid & 31, ks = tid >> 5;
  {  // GEMV k-partials: cols [ch*128+cg*4, +4), k in [ks*128, +128)
    f32x4 acc = (f32x4){0.f, 0.f, 0.f, 0.f};
    const float* Wq = p.W_qo + ch * 128 + cg * 4;
    const float* qr = qrow + ks * 128;
#pragma unroll 8
    for (int k = 0; k < 128; ++k) {
      f32x4 wv = *(const f32x4*)(Wq + (size_t)(ks * 128 + k) * 1024);
      FMA4(acc, qr[k], wv);
    }
    *(f32x4*)(pbuf + (ks * 32 + cg) * 4) = acc;
  }
  __syncthreads();
  if (tid < 32) {   // reduce 8 k-segments (ascending), add bias, emit
    f32x4 s = *(const f32x4*)(p.b_qo + ch * 128 + tid * 4);
#pragma unroll
    for (int k2 = 0; k2 < 8; ++k2) s += *(const f32x4*)(pbuf + (k2 * 32 + tid) * 4);
    *(f32x4*)(p.out_post + ((size_t)r * 64 + t) * 1024 + ch * 128 + tid * 4) = s;
    *(f32x4*)(ybuf + tid * 4) = s;
  }
  __syncthreads();
  if (t < 63 && tid < 4) {   // groups g = ch*4 + tid (32 cols, chunk-local)
    const float* rb = ybuf + tid * 32;
    float best = rb[0]; int bi = 0;
#pragma unroll
    for (int c = 1; c < 32; ++c) {
      float v = rb[c];
      if (v > best) { best = v; bi = c; }   // strict > keeps first index
    }
    p.sidxg[r * 32 + ch * 4 + tid] = bi;
  }
}

// K6: finx12 (t<63): WGs 0-31: x1/x2(t+1); WGs 32-63: x0fin(t+1). grid 64
__global__ __launch_bounds__(256, 2) void k_finx12(RPtrs p, int t) {
  __shared__ float red[8];
  __shared__ int sidx[32];
  const int wg = blockIdx.x;
  const int tid = threadIdx.x;
  if (wg >= 32) {
    act_fin(p.SX0, 1024, 16, wg - 32, p.g_in_deter,
            p.xact + (size_t)(wg - 32) * 3072, 1.f / 1024.f, red);
    return;
  }
  const int r = wg;
  if (tid < 32) sidx[tid] = p.sidxg[r * 32 + tid] & 31;
  __syncthreads();
  const float m = p.is_first[r * 64 + t + 1] ? 0.f : 1.f;
  const int c0 = tid * 4;
  f32x4 s1 = (f32x4){0.f, 0.f, 0.f, 0.f};
  if (m != 0.f) {
    for (int g = 0; g < 32; ++g)
      s1 += *(const f32x4*)(p.W_in_stoch + (size_t)(g * 32 + sidx[g]) * 1024 + c0);
  }
  f32x4 pre = *(const f32x4*)(p.b_in_stoch + c0) + s1 * m;
  float ss = pre[0]*pre[0] + pre[1]*pre[1] + pre[2]*pre[2] + pre[3]*pre[3];
#pragma unroll
  for (int o = 32; o > 0; o >>= 1) ss += __shfl_down(ss, o, 64);
  if ((tid & 63) == 0) red[tid >> 6] = ss;
  __syncthreads();
  if (tid == 0)
    red[4] = 1.f / sqrtf((red[0] + red[1] + red[2] + red[3]) * (1.f / 1024.f) + 1e-6f);
  __syncthreads();
  {
    float sc = red[4];
    f32x4 gg = *(const f32x4*)(p.g_in_stoch + c0);
    f32x4 v = pre * sc * gg;
#pragma unroll
    for (int k = 0; k < 4; ++k) v[k] = v[k] / (1.f + expf(-v[k]));
    *(f32x4*)(p.xact + (size_t)r * 3072 + 1024 + c0) = v;
  }
  __syncthreads();
  x2_row(p, t + 1, r, m, red);
}

// ---- epilogue: batched prior over all 2048 (b,t) rows ---------------------
__global__ __launch_bounds__(256, 2) void kb_p0(RPtrs p) {
  __shared__ __align__(16) float As[4352];
  int rb = blockIdx.x >> 2, ct = blockIdx.x & 3;   // rb 0..31 (64 rows each)
  LdPlain la{p.out_deters + (size_t)rb * 64 * 2048, 2048};
  gemm_big64(la, p.W_p0, 1024, ct * 256, 32,
             p.Abuf0 + (size_t)rb * 64 * 1024, 1024, p.b_p0, As);
}
__global__ __launch_bounds__(256, 2) void kb_fin0(RPtrs p) {
  __shared__ float red[8];
  for (int i = 0; i < 8; ++i) {
    int r = blockIdx.x * 8 + i;
    act_fin(p.Abuf0, 1024, 1, r, p.g_p0, p.Abuf1 + (size_t)r * 1024,
            1.f / 1024.f, red);
  }
}
__global__ __launch_bounds__(256, 2) void kb_p1(RPtrs p) {
  __shared__ __align__(16) float As[4352];
  int rb = blockIdx.x >> 2, ct = blockIdx.x & 3;
  LdPlain la{p.Abuf1 + (size_t)rb * 64 * 1024, 1024};
  gemm_big64(la, p.W_p1, 1024, ct * 256, 16,
             p.Abuf0 + (size_t)rb * 64 * 1024, 1024, p.b_p1, As);
}
__global__ __launch_bounds__(256, 2) void kb_fin1(RPtrs p) {
  __shared__ float red[8];
  for (int i = 0; i < 8; ++i) {
    int r = blockIdx.x * 8 + i;
    act_fin(p.Abuf0, 1024, 1, r, p.g_p1, p.Abuf1 + (size_t)r * 1024,
            1.f / 1024.f, red);
  }
}
__global__ __launch_bounds__(256, 2) void kb_po(RPtrs p) {
  __shared__ __align__(16) float As[4352];
  int rb = blockIdx.x >> 2, ct = blockIdx.x & 3;
  LdPlain la{p.Abuf1 + (size_t)rb * 64 * 1024, 1024};
  gemm_big64(la, p.W_po, 1024, ct * 256, 16,
             p.out_prior + (size_t)rb * 64 * 1024, 1024, p.b_po, As);
}

// ===========================================================================
extern "C" void kernel_launch(void* const* d_in, const int* in_sizes, int n_in,
                              void* d_out, int out_size, void* d_ws,
                              size_t ws_size, hipStream_t stream) {
  RPtrs p;
  p.embed      = (const float*)d_in[0];
  p.action     = (const float*)d_in[1];
  p.is_first   = (const int*)d_in[2];
  p.W_in_deter = (const float*)d_in[3];  p.b_in_deter = (const float*)d_in[4];  p.g_in_deter = (const float*)d_in[5];
  p.W_in_stoch = (const float*)d_in[6];  p.b_in_stoch = (const float*)d_in[7];  p.g_in_stoch = (const float*)d_in[8];
  p.W_in_act   = (const float*)d_in[9];  p.b_in_act   = (const float*)d_in[10]; p.g_in_act   = (const float*)d_in[11];
  p.W_dyn      = (const float*)d_in[12]; p.b_dyn      = (const float*)d_in[13]; p.g_dyn      = (const float*)d_in[14];
  p.W_gru      = (const float*)d_in[15]; p.b_gru      = (const float*)d_in[16];
  p.W_p0       = (const float*)d_in[17]; p.b_p0       = (const float*)d_in[18]; p.g_p0       = (const float*)d_in[19];
  p.W_p1       = (const float*)d_in[20]; p.b_p1       = (const float*)d_in[21]; p.g_p1       = (const float*)d_in[22];
  p.W_po       = (const float*)d_in[23]; p.b_po       = (const float*)d_in[24];
  p.W_q0       = (const float*)d_in[25]; p.b_q0       = (const float*)d_in[26]; p.g_q0       = (const float*)d_in[27];
  p.W_qo       = (const float*)d_in[28]; p.b_qo       = (const float*)d_in[29];

  float* o = (float*)d_out;
  p.out_post   = o;               // [32][64][1024]
  p.out_prior  = o + 2097152;     // [32][64][1024]
  p.out_deters = o + 4194304;     // [32][64][2048]

  float* w = (float*)d_ws;
  // loop-era layout (all dead by epilogue):
  p.deter  = w;                   // 65536
  p.determ = w + 65536;           // 65536
  p.xact   = w + 131072;          // 98304   [32][3072]
  p.hact   = w + 229376;          // 65536
  p.SDyn   = w + 393216;          // 1703936 [26][32][2048]
  p.SQ0    = w + 2097152;         // 786432  [24][32][1024]
  p.SX0    = w + 2883584;         // 524288  [16][32][1024]
  // epilogue-era layout (reuses loop buffers; strictly launch-ordered):
  p.Abuf0  = w;                   // 2097152 [2048][1024]
  p.Abuf1  = w + 2097152;         // 2097152 [2048][1024]
  p.sidxg  = (int*)(w + 4194304); // 1024
  // total 4195328 floats ~= 16.8 MB

  k_init<<<512, 256, 0, stream>>>(p);
  for (int t = 0; t < 64; ++t) {
    k_dyn<<<208, 256, 0, stream>>>(p, t);
    k_dynfin<<<32, 256, 0, stream>>>(p);
    k_gru<<<128, 256, 0, stream>>>(p, t);
    k_q0x0<<<160, 256, 0, stream>>>(p, t);
    k_qo256<<<256, 256, 0, stream>>>(p, t);
    if (t < 63) k_finx12<<<64, 256, 0, stream>>>(p, t);
  }
  kb_p0<<<128, 256, 0, stream>>>(p);
  kb_fin0<<<256, 256, 0, stream>>>(p);
  kb_p1<<<128, 256, 0, stream>>>(p);
  kb_fin1<<<256, 256, 0, stream>>>(p);
  kb_po<<<128, 256, 0, stream>>>(p);
}

// Round 15
// 6928.967 us; speedup vs baseline: 1.0676x; 1.0676x over previous
//
#include <hip/hip_runtime.h>
#include <math.h>

#define DEVINL __device__ __forceinline__
typedef float f32x4 __attribute__((ext_vector_type(4)));

// ---------------------------------------------------------------------------
// RSSM scan, multi-launch. R15 = exact R12 (best verified: 6.94 ms).
//   loop:  dyn(208) | dynfin(32) | gru(128) | q0+x0(160) | qo256(256) |
//          finx12(64)    -- 6 launches/step, grids <= 256
//   epilogue: batched prior (p0/p1/po) with 32-row tiles, 256 WGs each.
// R13/R14 lesson: 64-row epilogue tiles REGRESS (register-pressure cliff);
// grouped finalizers REGRESS (serial row chains). Keep 32-row + 1-row-per-WG.
// Launch boundaries are the only sync (in-kernel correct barrier >= 30us
// wbl2 floor > 12us launch gap; relaxed sync unsound on gfx950).
// fp32 throughout (bf16 would flip argmaxes -> cascading recurrence error).
// ---------------------------------------------------------------------------

struct RPtrs {
  const float *embed, *action; const int *is_first;
  const float *W_in_deter, *b_in_deter, *g_in_deter;
  const float *W_in_stoch, *b_in_stoch, *g_in_stoch;
  const float *W_in_act,   *b_in_act,   *g_in_act;
  const float *W_dyn, *b_dyn, *g_dyn;
  const float *W_gru, *b_gru;
  const float *W_p0, *b_p0, *g_p0;
  const float *W_p1, *b_p1, *g_p1;
  const float *W_po, *b_po;
  const float *W_q0, *b_q0, *g_q0;
  const float *W_qo, *b_qo;
  float *out_post, *out_prior, *out_deters;
  float *deter, *determ, *xact, *hact;
  float *SDyn, *SQ0, *SX0, *Abuf0, *Abuf1;
  int *sidxg;
};

// ---- A loaders ------------------------------------------------------------
struct LdPlain {
  const float* A; int lda;
  DEVINL const float* addr(int r, int k) const { return A + (size_t)r * lda + k; }
};
struct LdDyn {   // [dg(256 masked deter) | x(3072 activated)]
  const float* dm; const float* x; int blk;
  DEVINL const float* addr(int r, int k) const {
    return (k < 256) ? dm + (size_t)r * 2048 + blk * 256 + k
                     : x + (size_t)r * 3072 + (k - 256);
  }
};
struct LdQ0 {    // [deter(2048) | embed(1024)]
  const float* det; const float* emb; int t;
  DEVINL const float* addr(int r, int k) const {
    return (k < 2048) ? det + (size_t)r * 2048 + k
                      : emb + ((size_t)r * 64 + t) * 1024 + (k - 2048);
  }
};

#define FMA4(A, S, W) { (A)[0]=fmaf((S),(W)[0],(A)[0]); (A)[1]=fmaf((S),(W)[1],(A)[1]); \
                        (A)[2]=fmaf((S),(W)[2],(A)[2]); (A)[3]=fmaf((S),(W)[3],(A)[3]); }

// ---- GEMM (K-chunked, slab output): 256 cols x 32 rows x (NBLK*64) K ------
template <int NBLK, typename LA>
DEVINL void gemm_tile(LA la, const float* __restrict__ W, int ldw, int wcb,
                      int k0, float* __restrict__ slab, int sst, int scb,
                      const float* __restrict__ bias, float* As) {
  const int tid = threadIdx.x;
  const int c4 = (tid & 63) * 4;
  const int rg = (tid >> 6) * 8;
  const int srr = tid & 31;
  const int skk = (tid >> 5) * 8;
  f32x4 acc[8];
#pragma unroll
  for (int i = 0; i < 8; ++i) acc[i] = (f32x4){0.f, 0.f, 0.f, 0.f};
  const float* ap = la.addr(srr, k0 + skk);
  f32x4 cur0 = *(const f32x4*)ap;
  f32x4 cur1 = *(const f32x4*)(ap + 4);
#pragma unroll
  for (int b = 0; b < NBLK; ++b) {
    __syncthreads();
#pragma unroll
    for (int e = 0; e < 4; ++e) {
      As[(skk + e) * 36 + srr]     = cur0[e];
      As[(skk + 4 + e) * 36 + srr] = cur1[e];
    }
    f32x4 nxt0, nxt1;
    if (b + 1 < NBLK) {
      const float* np = la.addr(srr, k0 + (b + 1) * 64 + skk);
      nxt0 = *(const f32x4*)np;
      nxt1 = *(const f32x4*)(np + 4);
    }
    __syncthreads();
    const float* Wp = W + (size_t)(k0 + b * 64) * ldw + wcb + c4;
#pragma unroll 8
    for (int kk = 0; kk < 64; ++kk) {
      f32x4 w = *(const f32x4*)(Wp + (size_t)kk * ldw);
      const float* Ab = As + kk * 36 + rg;
      f32x4 alo = *(const f32x4*)(Ab);
      f32x4 ahi = *(const f32x4*)(Ab + 4);
      FMA4(acc[0], alo[0], w); FMA4(acc[1], alo[1], w);
      FMA4(acc[2], alo[2], w); FMA4(acc[3], alo[3], w);
      FMA4(acc[4], ahi[0], w); FMA4(acc[5], ahi[1], w);
      FMA4(acc[6], ahi[2], w); FMA4(acc[7], ahi[3], w);
    }
    if (b + 1 < NBLK) { cur0 = nxt0; cur1 = nxt1; }
  }
  f32x4 bv = (f32x4){0.f, 0.f, 0.f, 0.f};
  if (bias) bv = *(const f32x4*)(bias + wcb + c4);
#pragma unroll
  for (int i = 0; i < 8; ++i) {
    f32x4 o = acc[i] + bv;
    *(f32x4*)(slab + (size_t)(rg + i) * sst + scb + c4) = o;
  }
}

// ---- GEMM (full-K, direct output + bias): for batched epilogue ------------
template <typename LA>
DEVINL void gemm_big(LA la, const float* __restrict__ W, int ldw, int wcb,
                     int nblk, float* __restrict__ outp, int ost,
                     const float* __restrict__ bias, float* As) {
  const int tid = threadIdx.x;
  const int c4 = (tid & 63) * 4;
  const int rg = (tid >> 6) * 8;
  const int srr = tid & 31;
  const int skk = (tid >> 5) * 8;
  f32x4 acc[8];
#pragma unroll
  for (int i = 0; i < 8; ++i) acc[i] = (f32x4){0.f, 0.f, 0.f, 0.f};
  const float* ap = la.addr(srr, skk);
  f32x4 cur0 = *(const f32x4*)ap;
  f32x4 cur1 = *(const f32x4*)(ap + 4);
  f32x4 nxt0, nxt1;
  for (int b = 0; b < nblk; ++b) {
    __syncthreads();
#pragma unroll
    for (int e = 0; e < 4; ++e) {
      As[(skk + e) * 36 + srr]     = cur0[e];
      As[(skk + 4 + e) * 36 + srr] = cur1[e];
    }
    if (b + 1 < nblk) {
      const float* np = la.addr(srr, (b + 1) * 64 + skk);
      nxt0 = *(const f32x4*)np;
      nxt1 = *(const f32x4*)(np + 4);
    }
    __syncthreads();
    const float* Wp = W + (size_t)(b * 64) * ldw + wcb + c4;
#pragma unroll 8
    for (int kk = 0; kk < 64; ++kk) {
      f32x4 w = *(const f32x4*)(Wp + (size_t)kk * ldw);
      const float* Ab = As + kk * 36 + rg;
      f32x4 alo = *(const f32x4*)(Ab);
      f32x4 ahi = *(const f32x4*)(Ab + 4);
      FMA4(acc[0], alo[0], w); FMA4(acc[1], alo[1], w);
      FMA4(acc[2], alo[2], w); FMA4(acc[3], alo[3], w);
      FMA4(acc[4], ahi[0], w); FMA4(acc[5], ahi[1], w);
      FMA4(acc[6], ahi[2], w); FMA4(acc[7], ahi[3], w);
    }
    if (b + 1 < nblk) { cur0 = nxt0; cur1 = nxt1; }
  }
  f32x4 bv = *(const f32x4*)(bias + wcb + c4);
#pragma unroll
  for (int i = 0; i < 8; ++i) {
    f32x4 o = acc[i] + bv;
    *(f32x4*)(outp + (size_t)(rg + i) * ost + wcb + c4) = o;
  }
}

// ---- finalizer: y = sum chunks (regs, ascending), RMS, SiLU ---------------
DEVINL void act_fin(const float* __restrict__ slab, int N, int nch, int r,
                    const float* __restrict__ g, float* __restrict__ out,
                    float invN, float* red) {
  const int tid = threadIdx.x;
  const size_t cstr = (size_t)32 * N;
  const float* base = slab + (size_t)r * N + tid * 4;
  f32x4 y0 = (f32x4){0.f, 0.f, 0.f, 0.f}, y1 = y0;
  for (int ch = 0; ch < nch; ++ch)
    y0 += *(const f32x4*)(base + (size_t)ch * cstr);
  float ss = y0[0]*y0[0] + y0[1]*y0[1] + y0[2]*y0[2] + y0[3]*y0[3];
  if (N == 2048) {
    for (int ch = 0; ch < nch; ++ch)
      y1 += *(const f32x4*)(base + 1024 + (size_t)ch * cstr);
    ss += y1[0]*y1[0] + y1[1]*y1[1] + y1[2]*y1[2] + y1[3]*y1[3];
  }
#pragma unroll
  for (int o = 32; o > 0; o >>= 1) ss += __shfl_down(ss, o, 64);
  if ((tid & 63) == 0) red[tid >> 6] = ss;
  __syncthreads();
  if (tid == 0)
    red[4] = 1.f / sqrtf((red[0] + red[1] + red[2] + red[3]) * invN + 1e-6f);
  __syncthreads();
  const float sc = red[4];
  {
    f32x4 gg = *(const f32x4*)(g + tid * 4);
    f32x4 v = y0 * sc * gg;
#pragma unroll
    for (int k = 0; k < 4; ++k) v[k] = v[k] / (1.f + expf(-v[k]));
    *(f32x4*)(out + tid * 4) = v;
  }
  if (N == 2048) {
    f32x4 gg = *(const f32x4*)(g + 1024 + tid * 4);
    f32x4 v = y1 * sc * gg;
#pragma unroll
    for (int k = 0; k < 4; ++k) v[k] = v[k] / (1.f + expf(-v[k]));
    *(f32x4*)(out + 1024 + tid * 4) = v;
  }
}

DEVINL float sigm(float x) { return 1.f / (1.f + expf(-x)); }

// ---- x2 (action) pre-act + RMS + SiLU for row r, step tt ------------------
DEVINL void x2_row(const RPtrs& p, int tt, int r, float m, float* red) {
  const int tid = threadIdx.x;
  const int c0 = tid * 4;
  const float* arow = p.action + ((size_t)r * 64 + tt) * 16;
  f32x4 s2 = *(const f32x4*)(p.b_in_act + c0);
#pragma unroll
  for (int ii = 0; ii < 16; ++ii) {
    float av = arow[ii] * m;
    av = av / fmaxf(fabsf(av), 1.f);
    f32x4 wv = *(const f32x4*)(p.W_in_act + ii * 1024 + c0);
    FMA4(s2, av, wv);
  }
  float ss = s2[0]*s2[0] + s2[1]*s2[1] + s2[2]*s2[2] + s2[3]*s2[3];
#pragma unroll
  for (int o = 32; o > 0; o >>= 1) ss += __shfl_down(ss, o, 64);
  if ((tid & 63) == 0) red[tid >> 6] = ss;
  __syncthreads();
  if (tid == 0)
    red[4] = 1.f / sqrtf((red[0] + red[1] + red[2] + red[3]) * (1.f / 1024.f) + 1e-6f);
  __syncthreads();
  float sc = red[4];
  f32x4 gg = *(const f32x4*)(p.g_in_act + c0);
  f32x4 v = s2 * sc * gg;
#pragma unroll
  for (int k = 0; k < 4; ++k) v[k] = v[k] / (1.f + expf(-v[k]));
  *(f32x4*)(p.xact + (size_t)r * 3072 + 2048 + c0) = v;
}

// ---- bias-only pre-act + RMS + SiLU (for t=0: determ=0, stoch=0) ----------
DEVINL void bias_row(const float* __restrict__ b, const float* __restrict__ g,
                     float* __restrict__ out, float* red) {
  const int tid = threadIdx.x;
  const int c0 = tid * 4;
  f32x4 pre = *(const f32x4*)(b + c0);
  float ss = pre[0]*pre[0] + pre[1]*pre[1] + pre[2]*pre[2] + pre[3]*pre[3];
#pragma unroll
  for (int o = 32; o > 0; o >>= 1) ss += __shfl_down(ss, o, 64);
  if ((tid & 63) == 0) red[tid >> 6] = ss;
  __syncthreads();
  if (tid == 0)
    red[4] = 1.f / sqrtf((red[0] + red[1] + red[2] + red[3]) * (1.f / 1024.f) + 1e-6f);
  __syncthreads();
  float sc = red[4];
  f32x4 gg = *(const f32x4*)(g + c0);
  f32x4 v = pre * sc * gg;
#pragma unroll
  for (int k = 0; k < 4; ++k) v[k] = v[k] / (1.f + expf(-v[k]));
  *(f32x4*)(out + c0) = v;
}

// ===========================================================================
// K0: init + prologue. grid 512: WGs 0-255 zero state; WGs 480-511 xact(0)
__global__ __launch_bounds__(256) void k_init(RPtrs p) {
  __shared__ float red[8];
  const int wg = blockIdx.x;
  size_t i = (size_t)wg * 256 + threadIdx.x;
  if (i < 65536) { p.deter[i] = 0.f; p.determ[i] = 0.f; }
  if (wg >= 480) {
    const int r = wg - 480;
    bias_row(p.b_in_deter, p.g_in_deter, p.xact + (size_t)r * 3072, red);
    __syncthreads();
    bias_row(p.b_in_stoch, p.g_in_stoch, p.xact + (size_t)r * 3072 + 1024, red);
    __syncthreads();
    float m = p.is_first[r * 64] ? 0.f : 1.f;
    x2_row(p, 0, r, m, red);
  }
}

// K1: dyn. grid 208
__global__ __launch_bounds__(256, 2) void k_dyn(RPtrs p, int t) {
  __shared__ __align__(16) float As[2304];
  const int wg = blockIdx.x;
  int blk = wg / 26, kc = wg % 26;  // KC=128
  LdDyn la{p.determ, p.xact, blk};
  gemm_tile<2>(la, p.W_dyn + (size_t)blk * 851968, 256, 0, kc * 128,
               p.SDyn + (size_t)kc * 65536, 2048, blk * 256,
               kc == 0 ? p.b_dyn + blk * 256 : nullptr, As);
}

// K2: dynfin. grid 32
__global__ __launch_bounds__(256, 2) void k_dynfin(RPtrs p) {
  __shared__ float red[8];
  act_fin(p.SDyn, 2048, 26, blockIdx.x, p.g_dyn,
          p.hact + (size_t)blockIdx.x * 2048, 1.f / 2048.f, red);
}

// K3: gru. grid 128
__global__ __launch_bounds__(256, 2) void k_gru(RPtrs p, int t) {
  __shared__ float Al[8704];
  const int wg = blockIdx.x;
  const int blk = wg >> 4, jch = wg & 15;
  const int tid = threadIdx.x;
  {
    const float* hp = p.hact + blk * 256 + tid;
#pragma unroll
    for (int jb = 0; jb < 32; ++jb)
      Al[tid * 34 + jb] = hp[(size_t)jb * 2048];
  }
  __syncthreads();
  const int j = tid & 15, rg = tid >> 4;
  const int r0 = rg * 2;
  const int jcol = jch * 16 + j;
  const float* Wg = p.W_gru + (size_t)blk * 196608 + jcol;
  float r0a = 0, r1a = 0, c0a = 0, c1a = 0, u0a = 0, u1a = 0;
#pragma unroll 4
  for (int kk = 0; kk < 256; ++kk) {
    float wr = Wg[(size_t)kk * 768];
    float wc = Wg[(size_t)kk * 768 + 256];
    float wu = Wg[(size_t)kk * 768 + 512];
    float ax = Al[kk * 34 + r0], ay = Al[kk * 34 + r0 + 1];
    r0a = fmaf(ax, wr, r0a); r1a = fmaf(ay, wr, r1a);
    c0a = fmaf(ax, wc, c0a); c1a = fmaf(ay, wc, c1a);
    u0a = fmaf(ax, wu, u0a); u1a = fmaf(ay, wu, u1a);
  }
  const int col = blk * 256 + jcol;
  const float br = p.b_gru[blk * 768 + jcol];
  const float bc = p.b_gru[blk * 768 + 256 + jcol];
  const float bu = p.b_gru[blk * 768 + 512 + jcol];
#pragma unroll
  for (int rr = 0; rr < 2; ++rr) {
    int r = r0 + rr;
    float gr = (rr ? r1a : r0a) + br;
    float gc = (rr ? c1a : c0a) + bc;
    float gu = (rr ? u1a : u0a) + bu;
    float rs = sigm(gr);
    float cc = tanhf(rs * gc);
    float uu = sigm(gu - 1.f);
    float dg = p.determ[(size_t)r * 2048 + col];
    float nd = uu * cc + (1.f - uu) * dg;
    p.deter[(size_t)r * 2048 + col] = nd;
    p.out_deters[((size_t)r * 64 + t) * 2048 + col] = nd;
    float mn = 0.f;
    if (t + 1 < 64) mn = p.is_first[r * 64 + (t + 1)] ? 0.f : 1.f;
    p.determ[(size_t)r * 2048 + col] = nd * mn;
  }
}

// K4: q0 (0-95) + x0(t+1) (96-159). grid 160
__global__ __launch_bounds__(256, 2) void k_q0x0(RPtrs p, int t) {
  __shared__ __align__(16) float As[2304];
  const int wg = blockIdx.x;
  if (wg < 96) {
    int ct = wg & 3, kc = wg >> 2;   // kc 0..23, KC=128, K=3072
    LdQ0 la{p.deter, p.embed, t};
    gemm_tile<2>(la, p.W_q0, 1024, ct * 256, kc * 128,
                 p.SQ0 + (size_t)kc * 32768, 1024, ct * 256,
                 kc == 0 ? p.b_q0 : nullptr, As);
  } else {
    if (t >= 63) return;
    int i = wg - 96, ct = i & 3, kc = i >> 2;   // kc 0..15, K=2048
    LdPlain la{p.determ, 2048};
    gemm_tile<2>(la, p.W_in_deter, 1024, ct * 256, kc * 128,
                 p.SX0 + (size_t)kc * 32768, 1024, ct * 256,
                 kc == 0 ? p.b_in_deter : nullptr, As);
  }
}

// K5: qo256. WG = (row r = wg>>3, col-chunk ch = wg&7 of 128 cols).
// q0fin (redundant x8), chunked GEMV, post logits + local argmax. grid 256
__global__ __launch_bounds__(256, 2) void k_qo256(RPtrs p, int t) {
  __shared__ __align__(16) float smem[2184];
  float* qrow = smem;             // 1024
  float* pbuf = smem + 1024;      // 1024
  float* ybuf = smem + 2048;      // 128
  float* red  = smem + 2176;      // 8
  const int wg = blockIdx.x;
  const int r = wg >> 3, ch = wg & 7;
  const int tid = threadIdx.x;
  const int c0 = tid * 4;
  {  // q0fin -> qrow (ascending chunk order)
    const float* base = p.SQ0 + (size_t)r * 1024 + c0;
    f32x4 y = (f32x4){0.f, 0.f, 0.f, 0.f};
#pragma unroll
    for (int cc = 0; cc < 24; ++cc) y += *(const f32x4*)(base + (size_t)cc * 32768);
    float ss = y[0]*y[0] + y[1]*y[1] + y[2]*y[2] + y[3]*y[3];
#pragma unroll
    for (int o = 32; o > 0; o >>= 1) ss += __shfl_down(ss, o, 64);
    if ((tid & 63) == 0) red[tid >> 6] = ss;
    __syncthreads();
    if (tid == 0)
      red[4] = 1.f / sqrtf((red[0] + red[1] + red[2] + red[3]) * (1.f / 1024.f) + 1e-6f);
    __syncthreads();
    float sc = red[4];
    f32x4 gg = *(const f32x4*)(p.g_q0 + c0);
    f32x4 v = y * sc * gg;
#pragma unroll
    for (int k = 0; k < 4; ++k) v[k] = v[k] / (1.f + expf(-v[k]));
    *(f32x4*)(qrow + c0) = v;
  }
  __syncthreads();
  const int cg = tid & 31, ks = tid >> 5;
  {  // GEMV k-partials: cols [ch*128+cg*4, +4), k in [ks*128, +128)
    f32x4 acc = (f32x4){0.f, 0.f, 0.f, 0.f};
    const float* Wq = p.W_qo + ch * 128 + cg * 4;
    const float* qr = qrow + ks * 128;
#pragma unroll 8
    for (int k = 0; k < 128; ++k) {
      f32x4 wv = *(const f32x4*)(Wq + (size_t)(ks * 128 + k) * 1024);
      FMA4(acc, qr[k], wv);
    }
    *(f32x4*)(pbuf + (ks * 32 + cg) * 4) = acc;
  }
  __syncthreads();
  if (tid < 32) {   // reduce 8 k-segments (ascending), add bias, emit
    f32x4 s = *(const f32x4*)(p.b_qo + ch * 128 + tid * 4);
#pragma unroll
    for (int k2 = 0; k2 < 8; ++k2) s += *(const f32x4*)(pbuf + (k2 * 32 + tid) * 4);
    *(f32x4*)(p.out_post + ((size_t)r * 64 + t) * 1024 + ch * 128 + tid * 4) = s;
    *(f32x4*)(ybuf + tid * 4) = s;
  }
  __syncthreads();
  if (t < 63 && tid < 4) {   // groups g = ch*4 + tid (32 cols, chunk-local)
    const float* rb = ybuf + tid * 32;
    float best = rb[0]; int bi = 0;
#pragma unroll
    for (int c = 1; c < 32; ++c) {
      float v = rb[c];
      if (v > best) { best = v; bi = c; }   // strict > keeps first index
    }
    p.sidxg[r * 32 + ch * 4 + tid] = bi;
  }
}

// K6: finx12 (t<63): WGs 0-31: x1/x2(t+1); WGs 32-63: x0fin(t+1). grid 64
__global__ __launch_bounds__(256, 2) void k_finx12(RPtrs p, int t) {
  __shared__ float red[8];
  __shared__ int sidx[32];
  const int wg = blockIdx.x;
  const int tid = threadIdx.x;
  if (wg >= 32) {
    act_fin(p.SX0, 1024, 16, wg - 32, p.g_in_deter,
            p.xact + (size_t)(wg - 32) * 3072, 1.f / 1024.f, red);
    return;
  }
  const int r = wg;
  if (tid < 32) sidx[tid] = p.sidxg[r * 32 + tid] & 31;
  __syncthreads();
  const float m = p.is_first[r * 64 + t + 1] ? 0.f : 1.f;
  const int c0 = tid * 4;
  f32x4 s1 = (f32x4){0.f, 0.f, 0.f, 0.f};
  if (m != 0.f) {
    for (int g = 0; g < 32; ++g)
      s1 += *(const f32x4*)(p.W_in_stoch + (size_t)(g * 32 + sidx[g]) * 1024 + c0);
  }
  f32x4 pre = *(const f32x4*)(p.b_in_stoch + c0) + s1 * m;
  float ss = pre[0]*pre[0] + pre[1]*pre[1] + pre[2]*pre[2] + pre[3]*pre[3];
#pragma unroll
  for (int o = 32; o > 0; o >>= 1) ss += __shfl_down(ss, o, 64);
  if ((tid & 63) == 0) red[tid >> 6] = ss;
  __syncthreads();
  if (tid == 0)
    red[4] = 1.f / sqrtf((red[0] + red[1] + red[2] + red[3]) * (1.f / 1024.f) + 1e-6f);
  __syncthreads();
  {
    float sc = red[4];
    f32x4 gg = *(const f32x4*)(p.g_in_stoch + c0);
    f32x4 v = pre * sc * gg;
#pragma unroll
    for (int k = 0; k < 4; ++k) v[k] = v[k] / (1.f + expf(-v[k]));
    *(f32x4*)(p.xact + (size_t)r * 3072 + 1024 + c0) = v;
  }
  __syncthreads();
  x2_row(p, t + 1, r, m, red);
}

// ---- epilogue: batched prior over all 2048 (b,t) rows ---------------------
__global__ __launch_bounds__(256, 2) void kb_p0(RPtrs p) {
  __shared__ __align__(16) float As[2304];
  int rb = blockIdx.x >> 2, ct = blockIdx.x & 3;
  LdPlain la{p.out_deters + (size_t)rb * 32 * 2048, 2048};
  gemm_big(la, p.W_p0, 1024, ct * 256, 32,
           p.Abuf0 + (size_t)rb * 32 * 1024, 1024, p.b_p0, As);
}
__global__ __launch_bounds__(256, 2) void kb_fin0(RPtrs p) {
  __shared__ float red[8];
  int r = blockIdx.x;
  act_fin(p.Abuf0, 1024, 1, r, p.g_p0, p.Abuf1 + (size_t)r * 1024,
          1.f / 1024.f, red);
}
__global__ __launch_bounds__(256, 2) void kb_p1(RPtrs p) {
  __shared__ __align__(16) float As[2304];
  int rb = blockIdx.x >> 2, ct = blockIdx.x & 3;
  LdPlain la{p.Abuf1 + (size_t)rb * 32 * 1024, 1024};
  gemm_big(la, p.W_p1, 1024, ct * 256, 16,
           p.Abuf0 + (size_t)rb * 32 * 1024, 1024, p.b_p1, As);
}
__global__ __launch_bounds__(256, 2) void kb_fin1(RPtrs p) {
  __shared__ float red[8];
  int r = blockIdx.x;
  act_fin(p.Abuf0, 1024, 1, r, p.g_p1, p.Abuf1 + (size_t)r * 1024,
          1.f / 1024.f, red);
}
__global__ __launch_bounds__(256, 2) void kb_po(RPtrs p) {
  __shared__ __align__(16) float As[2304];
  int rb = blockIdx.x >> 2, ct = blockIdx.x & 3;
  LdPlain la{p.Abuf1 + (size_t)rb * 32 * 1024, 1024};
  gemm_big(la, p.W_po, 1024, ct * 256, 16,
           p.out_prior + (size_t)rb * 32 * 1024, 1024, p.b_po, As);
}

// ===========================================================================
extern "C" void kernel_launch(void* const* d_in, const int* in_sizes, int n_in,
                              void* d_out, int out_size, void* d_ws,
                              size_t ws_size, hipStream_t stream) {
  RPtrs p;
  p.embed      = (const float*)d_in[0];
  p.action     = (const float*)d_in[1];
  p.is_first   = (const int*)d_in[2];
  p.W_in_deter = (const float*)d_in[3];  p.b_in_deter = (const float*)d_in[4];  p.g_in_deter = (const float*)d_in[5];
  p.W_in_stoch = (const float*)d_in[6];  p.b_in_stoch = (const float*)d_in[7];  p.g_in_stoch = (const float*)d_in[8];
  p.W_in_act   = (const float*)d_in[9];  p.b_in_act   = (const float*)d_in[10]; p.g_in_act   = (const float*)d_in[11];
  p.W_dyn      = (const float*)d_in[12]; p.b_dyn      = (const float*)d_in[13]; p.g_dyn      = (const float*)d_in[14];
  p.W_gru      = (const float*)d_in[15]; p.b_gru      = (const float*)d_in[16];
  p.W_p0       = (const float*)d_in[17]; p.b_p0       = (const float*)d_in[18]; p.g_p0       = (const float*)d_in[19];
  p.W_p1       = (const float*)d_in[20]; p.b_p1       = (const float*)d_in[21]; p.g_p1       = (const float*)d_in[22];
  p.W_po       = (const float*)d_in[23]; p.b_po       = (const float*)d_in[24];
  p.W_q0       = (const float*)d_in[25]; p.b_q0       = (const float*)d_in[26]; p.g_q0       = (const float*)d_in[27];
  p.W_qo       = (const float*)d_in[28]; p.b_qo       = (const float*)d_in[29];

  float* o = (float*)d_out;
  p.out_post   = o;               // [32][64][1024]
  p.out_prior  = o + 2097152;     // [32][64][1024]
  p.out_deters = o + 4194304;     // [32][64][2048]

  float* w = (float*)d_ws;
  // loop-era layout (all dead by epilogue):
  p.deter  = w;                   // 65536
  p.determ = w + 65536;           // 65536
  p.xact   = w + 131072;          // 98304   [32][3072]
  p.hact   = w + 229376;          // 65536
  p.SDyn   = w + 393216;          // 1703936 [26][32][2048]
  p.SQ0    = w + 2097152;         // 786432  [24][32][1024]
  p.SX0    = w + 2883584;         // 524288  [16][32][1024]
  // epilogue-era layout (reuses loop buffers; strictly launch-ordered):
  p.Abuf0  = w;                   // 2097152 [2048][1024]
  p.Abuf1  = w + 2097152;         // 2097152 [2048][1024]
  p.sidxg  = (int*)(w + 4194304); // 1024
  // total 4195328 floats ~= 16.8 MB

  k_init<<<512, 256, 0, stream>>>(p);
  for (int t = 0; t < 64; ++t) {
    k_dyn<<<208, 256, 0, stream>>>(p, t);
    k_dynfin<<<32, 256, 0, stream>>>(p);
    k_gru<<<128, 256, 0, stream>>>(p, t);
    k_q0x0<<<160, 256, 0, stream>>>(p, t);
    k_qo256<<<256, 256, 0, stream>>>(p, t);
    if (t < 63) k_finx12<<<64, 256, 0, stream>>>(p, t);
  }
  kb_p0<<<256, 256, 0, stream>>>(p);
  kb_fin0<<<2048, 256, 0, stream>>>(p);
  kb_p1<<<256, 256, 0, stream>>>(p);
  kb_fin1<<<2048, 256, 0, stream>>>(p);
  kb_po<<<256, 256, 0, stream>>>(p);
}